// Round 20
// baseline (115.129 us; speedup 1.0000x reference)
//
#include <hip/hip_runtime.h>

typedef __bf16 bf16_t;
typedef __bf16 bf16x8 __attribute__((ext_vector_type(8)));
typedef __bf16 bf16x4 __attribute__((ext_vector_type(4)));
typedef float f32x4 __attribute__((ext_vector_type(4)));
typedef float f32x16 __attribute__((ext_vector_type(16)));

#define MFMA16(a, b, c) __builtin_amdgcn_mfma_f32_16x16x32_bf16((a), (b), (c), 0, 0, 0)
#define MFMA32(a, b, c) __builtin_amdgcn_mfma_f32_32x32x16_bf16((a), (b), (c), 0, 0, 0)
#define EXP2(x) __builtin_amdgcn_exp2f(x)

typedef __attribute__((address_space(1))) const void gconst_as;
typedef __attribute__((address_space(3))) void lds_as;
// 16B-per-lane async global->LDS copy (dest = wave-uniform base + lane*16)
#define GLOAD_LDS16(g, s) \
    __builtin_amdgcn_global_load_lds((gconst_as*)(g), (lds_as*)(s), 16, 0, 0)

namespace {
constexpr int S_LEN = 2048;
constexpr int EMB   = 1024;
constexpr int HEADS = 16;
constexpr int HD    = 64;
constexpr float Q_PRESCALE = 1.44269504088896340736f / 32.0f;
constexpr float NEG_L2     = -4.5084e18f;   // -1e20 * log2(e)/32 -> exp2 = 0
}

__device__ __forceinline__ bf16x8 load8_cvt(const float* __restrict__ p) {
    const f32x4 a = *(const f32x4*)p;
    const f32x4 b = *(const f32x4*)(p + 4);
    bf16x8 r;
    r[0] = (bf16_t)a[0]; r[1] = (bf16_t)a[1]; r[2] = (bf16_t)a[2]; r[3] = (bf16_t)a[3];
    r[4] = (bf16_t)b[0]; r[5] = (bf16_t)b[1]; r[6] = (bf16_t)b[2]; r[7] = (bf16_t)b[3];
    return r;
}

__device__ __forceinline__ unsigned pk_bf16(float lo, float hi) {
    union { bf16_t h[2]; unsigned u; } u;
    u.h[0] = (bf16_t)lo; u.h[1] = (bf16_t)hi;
    return u.u;
}

// --------------------------------------------------------------------------
// Kernel 1: per-head projections (fp32 in -> bf16 out). Unchanged.
//   Qp row-major; Kf/Vf in MFMA-fragment-major order (lane-contiguous;
//   each 64-key tile = 8KB contiguous -> linear LDS staging possible).
// --------------------------------------------------------------------------
__global__ __launch_bounds__(256) void proj_kernel(
    const float* __restrict__ values, const float* __restrict__ keys,
    const float* __restrict__ queries,
    const float* __restrict__ Wv, const float* __restrict__ Wk,
    const float* __restrict__ Wq,
    bf16_t* __restrict__ Qp, bf16_t* __restrict__ Kf, bf16_t* __restrict__ Vf)
{
    const int tid = threadIdx.x;
    const int w = tid >> 6, l = tid & 63, g = l >> 4, q15 = l & 15;
    const int b   = blockIdx.x;
    const int mat = b >> 10;
    const int rem = b & 1023;
    const int h   = rem >> 6;
    const int t0  = (((rem & 63) << 2) + w) << 4;
    const int n   = t0 >> 11;
    const int s0  = t0 & 2047;

    if (mat < 2) {
        const float* X = (mat == 0) ? queries : keys;
        const float* W = (mat == 0) ? Wq : Wk;
        const float scl = (mat == 0) ? Q_PRESCALE : 1.0f;
        const float* xr = X + (size_t)(t0 + q15) * EMB + h * HD + g * 8;
        bf16x8 a0 = load8_cvt(xr);
        bf16x8 a1 = load8_cvt(xr + 32);
        f32x4 acc[4];
        #pragma unroll
        for (int nt = 0; nt < 4; ++nt) acc[nt] = (f32x4){0.f, 0.f, 0.f, 0.f};
        #pragma unroll
        for (int nt = 0; nt < 4; ++nt) {
            const float* wr = W + (nt * 16 + q15) * HD + g * 8;
            bf16x8 b0 = load8_cvt(wr);
            bf16x8 b1 = load8_cvt(wr + 32);
            acc[nt] = MFMA16(a0, b0, acc[nt]);
            acc[nt] = MFMA16(a1, b1, acc[nt]);
        }
        if (mat == 0) {
            bf16_t* O = Qp + (size_t)(n * HEADS + h) * S_LEN * HD;
            #pragma unroll
            for (int nt = 0; nt < 4; ++nt)
                #pragma unroll
                for (int r = 0; r < 4; ++r)
                    O[(size_t)(s0 + g * 4 + r) * HD + nt * 16 + q15] = (bf16_t)(acc[nt][r] * scl);
        } else {
            bf16_t* O = Kf + (size_t)(n * HEADS + h) * S_LEN * HD;
            const int ktb  = s0 >> 5;
            const int lrow = s0 & 31;
            const int hi8  = (q15 >> 3) * 256 + (q15 & 7);
            #pragma unroll
            for (int nt = 0; nt < 4; ++nt)
                #pragma unroll
                for (int r = 0; r < 4; ++r)
                    O[(size_t)(ktb * 4 + nt) * 512 + hi8 + (lrow + g * 4 + r) * 8]
                        = (bf16_t)acc[nt][r];
        }
    } else {
        const float* xr = values + (size_t)(t0 + q15) * EMB + h * HD + g * 8;
        bf16x8 b0 = load8_cvt(xr);
        bf16x8 b1 = load8_cvt(xr + 32);
        bf16_t* O = Vf + (size_t)(n * HEADS + h) * S_LEN * HD;
        f32x4 acc[4];
        #pragma unroll
        for (int et = 0; et < 4; ++et) acc[et] = (f32x4){0.f, 0.f, 0.f, 0.f};
        #pragma unroll
        for (int et = 0; et < 4; ++et) {
            const float* wr = Wv + (et * 16 + q15) * HD + g * 8;
            bf16x8 a0 = load8_cvt(wr);
            bf16x8 a1 = load8_cvt(wr + 32);
            acc[et] = MFMA16(a0, b0, acc[et]);
            acc[et] = MFMA16(a1, b1, acc[et]);
        }
        const int kt2 = (s0 >> 6) * 2;
        const int ksl = (s0 >> 4) & 3;
        const int hi8 = (q15 >> 3) * 256 + (q15 & 7);
        #pragma unroll
        for (int et = 0; et < 4; ++et)
            #pragma unroll
            for (int r = 0; r < 4; ++r)
                O[(size_t)((kt2 + (et >> 1)) * 4 + ksl) * 512 + hi8
                  + ((et & 1) * 16 + g * 4 + r) * 8] = (bf16_t)acc[et][r];
    }
}

// --------------------------------------------------------------------------
// Kernel 2: flash attention — r19 body + LDS-staged K/V double-buffer.
// The 4 waves of a block share each KV tile: stage it ONCE per block via
// global_load_lds (zero VGPR cost, 8KB K + 8KB V per tile, linear dest),
// double-buffered with ONE __syncthreads per tile (conservative 2-phase:
// barrier at end of tile t guarantees (a) all waves done reading buf[cur],
// (b) tile t+1's loads into buf[cur^1] have landed). Removes the per-tile
// kf L2-latency wait from the serial chain and cuts K/V L2 requests 4x.
// Fragment ds_reads are contiguous-b128 (conflict-free). T5 setprio kept.
// --------------------------------------------------------------------------
__global__ __launch_bounds__(256, 3) void attn_kernel(
    const bf16_t* __restrict__ Qp, const bf16_t* __restrict__ Kf,
    const bf16_t* __restrict__ Vf, const int* __restrict__ mask,
    bf16_t* __restrict__ AO)
{
    __shared__ bf16_t Kbuf[2][4096];     // 8KB per buffer
    __shared__ bf16_t Vbuf[2][4096];
    __shared__ bf16_t plds[4][32][72];   // epilogue transpose only
    const int tid = threadIdx.x;
    const int w = tid >> 6, l = tid & 63;
    const int l31 = l & 31, hi = l >> 5;
    const int bid = blockIdx.x;
    const int nh = bid & 31, qt = bid >> 5;
    const int n = nh >> 4, h = nh & 15;
    const size_t hb = (size_t)nh * S_LEN * HD;
    const int qb = qt * 128 + w * 32;

    bf16x8 qf[4];
    {
        const bf16_t* qr = Qp + hb + (size_t)(qb + l31) * HD + hi * 8;
        #pragma unroll
        for (int d = 0; d < 4; ++d) qf[d] = *(const bf16x8*)(qr + d * 16);
    }

    const int* __restrict__ mrow = mask + n * S_LEN;
    const bf16_t* kgbase = Kf + hb + (size_t)l * 8;   // + kt*4096 + j*512
    const bf16_t* vgbase = Vf + hb + (size_t)l * 8;

    bool anyZero = false;
    {
        const int* mp = mrow + (l >> 1) * 64 + (l & 1) * 32;
        #pragma unroll
        for (int j = 0; j < 8; ++j) {
            const int4 mv = *(const int4*)(mp + 4 * j);
            anyZero |= (mv.x == 0) | (mv.y == 0) | (mv.z == 0) | (mv.w == 0);
        }
    }
    const unsigned long long maskbal = __ballot(anyZero);

    // stage tile kt into buf b: wave w covers j-slices {2w, 2w+1} of K and V
    auto stage = [&](int b, int kt) {
        const size_t tb = (size_t)kt * 4096;
        #pragma unroll
        for (int s = 0; s < 2; ++s) {
            const int j = 2 * w + s;
            GLOAD_LDS16(kgbase + tb + j * 512, &Kbuf[b][j * 512]);
            GLOAD_LDS16(vgbase + tb + j * 512, &Vbuf[b][j * 512]);
        }
    };

    f32x16 acc0, acc1;
    #pragma unroll
    for (int i = 0; i < 16; ++i) { acc0[i] = 0.f; acc1[i] = 0.f; }
    float l_run = 0.0f;

    stage(0, 0);
    __syncthreads();               // drain prologue loads (all waves)
    int cur = 0;

    for (int kt = 0; kt < 32; ++kt) {
        // issue next tile's staging first (covered by this tile's body)
        if (kt + 1 < 32) stage(cur ^ 1, kt + 1);

        // fragments from LDS (contiguous b128, conflict-free)
        bf16x8 kf[8], vf[8];
        {
            const bf16_t* pk = &Kbuf[cur][l * 8];
            const bf16_t* pv = &Vbuf[cur][l * 8];
            #pragma unroll
            for (int j = 0; j < 8; ++j) kf[j] = *(const bf16x8*)(pk + j * 512);
            #pragma unroll
            for (int j = 0; j < 8; ++j) vf[j] = *(const bf16x8*)(pv + j * 512);
        }

        // S^T = K · Q^T : two 32x32 blocks over 4 d-steps each
        f32x16 s0, s1;
        #pragma unroll
        for (int i = 0; i < 16; ++i) { s0[i] = 0.f; s1[i] = 0.f; }
        __builtin_amdgcn_s_setprio(1);
        #pragma unroll
        for (int d = 0; d < 4; ++d) s0 = MFMA32(kf[d],     qf[d], s0);
        #pragma unroll
        for (int d = 0; d < 4; ++d) s1 = MFMA32(kf[4 + d], qf[d], s1);
        __builtin_amdgcn_s_setprio(0);

        // masking: wave-uniform scalar test, rare path only
        if ((maskbal >> (2 * kt)) & 3ull) {
            const unsigned long long mb = __ballot(mrow[kt * 64 + l] != 0);
            #pragma unroll
            for (int r = 0; r < 16; ++r) {
                const int cr = (r & 3) + 8 * (r >> 2) + 4 * hi;
                if (!((mb >> cr) & 1ull))        s0[r] = NEG_L2;
                if (!((mb >> (32 + cr)) & 1ull)) s1[r] = NEG_L2;
            }
        }

        // p = exp2(s) via raw v_exp_f32; l accumulates per half-lane
        float ts0 = 0.f, ts1 = 0.f;
        #pragma unroll
        for (int r = 0; r < 16; ++r) {
            const float p0 = EXP2(s0[r]);
            const float p1 = EXP2(s1[r]);
            s0[r] = p0; s1[r] = p1;
            ts0 += p0; ts1 += p1;
        }
        l_run += ts0 + ts1;

        // P -> PV A-fragments: 2 shfl + selects per (b,t), in-register
        union U8 { unsigned u[4]; bf16x8 v; };
        bf16x8 pa[4];
        #pragma unroll
        for (int b = 0; b < 2; ++b) {
            #pragma unroll
            for (int t = 0; t < 2; ++t) {
                const int rb = t * 8;
                float e0, e1, e2, e3, e4, e5, e6, e7;
                if (b == 0) {
                    e0 = s0[rb]; e1 = s0[rb + 1]; e2 = s0[rb + 2]; e3 = s0[rb + 3];
                    e4 = s0[rb + 4]; e5 = s0[rb + 5]; e6 = s0[rb + 6]; e7 = s0[rb + 7];
                } else {
                    e0 = s1[rb]; e1 = s1[rb + 1]; e2 = s1[rb + 2]; e3 = s1[rb + 3];
                    e4 = s1[rb + 4]; e5 = s1[rb + 5]; e6 = s1[rb + 6]; e7 = s1[rb + 7];
                }
                const unsigned a01 = pk_bf16(e0, e1);
                const unsigned a23 = pk_bf16(e2, e3);
                const unsigned b01 = pk_bf16(e4, e5);
                const unsigned b23 = pk_bf16(e6, e7);
                const unsigned y1 = hi ? a01 : b01;
                const unsigned y2 = hi ? a23 : b23;
                const unsigned r1 = (unsigned)__shfl_xor((int)y1, 32);
                const unsigned r2 = (unsigned)__shfl_xor((int)y2, 32);
                U8 f;
                f.u[0] = hi ? r1 : a01;
                f.u[1] = hi ? r2 : a23;
                f.u[2] = hi ? b01 : r1;
                f.u[3] = hi ? b23 : r2;
                pa[2 * b + t] = f.v;
            }
        }

        __builtin_amdgcn_s_setprio(1);
        #pragma unroll
        for (int ksl = 0; ksl < 4; ++ksl) {
            acc0 = MFMA32(pa[ksl], vf[ksl],     acc0);
            acc1 = MFMA32(pa[ksl], vf[4 + ksl], acc1);
        }
        __builtin_amdgcn_s_setprio(0);

        // barrier: (a) all waves done reading buf[cur]; (b) next tile's
        // staging (issued at tile top) has landed (syncthreads drains vmcnt)
        __syncthreads();
        cur ^= 1;
    }

    // epilogue: normalize, per-wave LDS transpose behind __syncthreads,
    // coalesced AO write
    const float l_tot = l_run + __shfl_xor(l_run, 32);   // per q = l31
    const float inv = 1.0f / l_tot;
    #pragma unroll
    for (int r = 0; r < 16; ++r) {
        const int cr = (r & 3) + 8 * (r >> 2) + 4 * hi;
        const float iq = __shfl(inv, cr);
        plds[w][cr][l31]      = (bf16_t)(acc0[r] * iq);
        plds[w][cr][32 + l31] = (bf16_t)(acc1[r] * iq);
    }
    __syncthreads();
    const int rr = l >> 1, c0 = (l & 1) * 32;
    const bf16x8 o0 = *(const bf16x8*)&plds[w][rr][c0];
    const bf16x8 o1 = *(const bf16x8*)&plds[w][rr][c0 + 8];
    const bf16x8 o2 = *(const bf16x8*)&plds[w][rr][c0 + 16];
    const bf16x8 o3 = *(const bf16x8*)&plds[w][rr][c0 + 24];
    bf16_t* op = AO + (size_t)(n * S_LEN + qb + rr) * EMB + h * HD + c0;
    *(bf16x8*)(op)      = o0;
    *(bf16x8*)(op + 8)  = o1;
    *(bf16x8*)(op + 16) = o2;
    *(bf16x8*)(op + 24) = o3;
}

// --------------------------------------------------------------------------
// Kernel 3: out = AO @ Wo^T + bo.  M=4096, N=1024, K=1024. fp32 out.
// 128x64 tile (512 blocks), BK=64, 4 waves (2x2, each 64x32). Unchanged.
// --------------------------------------------------------------------------
__global__ __launch_bounds__(256) void outproj_kernel(
    const bf16_t* __restrict__ X, const float* __restrict__ Wo,
    const float* __restrict__ bo, float* __restrict__ out)
{
    __shared__ bf16_t Xs[128 * 64];
    __shared__ bf16_t Ws[64 * 64];
    const int tid = threadIdx.x;
    const int w = tid >> 6, l = tid & 63, g = l >> 4, q15 = l & 15;
    const int m0 = (blockIdx.x >> 4) * 128;
    const int n0 = (blockIdx.x & 15) * 64;
    const int wm = (w >> 1) * 64, wn = (w & 1) * 32;

    f32x4 acc[4][2];
    #pragma unroll
    for (int i = 0; i < 4; ++i)
        #pragma unroll
        for (int j = 0; j < 2; ++j) acc[i][j] = (f32x4){0.f, 0.f, 0.f, 0.f};

    for (int k0 = 0; k0 < EMB; k0 += 64) {
        __syncthreads();
        #pragma unroll
        for (int j = 0; j < 4; ++j) {
            const int cid = tid + 256 * j;
            const int r = cid >> 3, pc = cid & 7;
            const int sw = (pc ^ (r & 7)) * 8;
            *(bf16x8*)&Xs[r * 64 + sw] =
                *(const bf16x8*)(X + (size_t)(m0 + r) * EMB + k0 + pc * 8);
        }
        #pragma unroll
        for (int j = 0; j < 2; ++j) {
            const int cid = tid + 256 * j;
            const int r = cid >> 3, pc = cid & 7;
            const int sw = (pc ^ (r & 7)) * 8;
            *(bf16x8*)&Ws[r * 64 + sw] =
                load8_cvt(Wo + (size_t)(n0 + r) * EMB + k0 + pc * 8);
        }
        __syncthreads();
        #pragma unroll
        for (int c = 0; c < 2; ++c) {
            bf16x8 av[4], bv[2];
            #pragma unroll
            for (int mt = 0; mt < 4; ++mt) {
                const int r = wm + mt * 16 + q15;
                av[mt] = *(const bf16x8*)&Xs[r * 64 + (((4 * c + g) ^ (r & 7)) * 8)];
            }
            #pragma unroll
            for (int nt = 0; nt < 2; ++nt) {
                const int r = wn + nt * 16 + q15;
                bv[nt] = *(const bf16x8*)&Ws[r * 64 + (((4 * c + g) ^ (r & 7)) * 8)];
            }
            #pragma unroll
            for (int mt = 0; mt < 4; ++mt)
                #pragma unroll
                for (int nt = 0; nt < 2; ++nt)
                    acc[mt][nt] = MFMA16(av[mt], bv[nt], acc[mt][nt]);
        }
    }

    float bias[2];
    #pragma unroll
    for (int nt = 0; nt < 2; ++nt) bias[nt] = bo[n0 + wn + nt * 16 + q15];
    #pragma unroll
    for (int mt = 0; mt < 4; ++mt)
        #pragma unroll
        for (int nt = 0; nt < 2; ++nt)
            #pragma unroll
            for (int r = 0; r < 4; ++r)
                out[(size_t)(m0 + wm + mt * 16 + g * 4 + r) * EMB + n0 + wn + nt * 16 + q15]
                    = acc[mt][nt][r] + bias[nt];
}

// --------------------------------------------------------------------------
extern "C" void kernel_launch(void* const* d_in, const int* in_sizes, int n_in,
                              void* d_out, int out_size, void* d_ws, size_t ws_size,
                              hipStream_t stream) {
    const float* values  = (const float*)d_in[0];
    const float* keys    = (const float*)d_in[1];
    const float* queries = (const float*)d_in[2];
    const int*   mask    = (const int*)d_in[3];
    const float* Wv      = (const float*)d_in[4];
    const float* Wk      = (const float*)d_in[5];
    const float* Wq      = (const float*)d_in[6];
    const float* Wo      = (const float*)d_in[7];
    const float* bo      = (const float*)d_in[8];
    float* out = (float*)d_out;

    // ws layout (bf16 elems): Qp[0,4M) Kf[4M,8M) Vf[8M,12M) AO[12M,16M)
    bf16_t* Qp = (bf16_t*)d_ws;
    bf16_t* Kf = Qp + (size_t)4194304;
    bf16_t* Vf = Kf + (size_t)4194304;
    bf16_t* AO = Vf + (size_t)4194304;

    proj_kernel<<<3072, 256, 0, stream>>>(values, keys, queries, Wv, Wk, Wq, Qp, Kf, Vf);
    attn_kernel<<<512, 256, 0, stream>>>(Qp, Kf, Vf, mask, AO);
    outproj_kernel<<<512, 256, 0, stream>>>(AO, Wo, bo, out);
}

// Round 21
// 112.607 us; speedup vs baseline: 1.0224x; 1.0224x over previous
//
#include <hip/hip_runtime.h>

typedef __bf16 bf16_t;
typedef __bf16 bf16x8 __attribute__((ext_vector_type(8)));
typedef __bf16 bf16x4 __attribute__((ext_vector_type(4)));
typedef float f32x4 __attribute__((ext_vector_type(4)));
typedef float f32x16 __attribute__((ext_vector_type(16)));

#define MFMA16(a, b, c) __builtin_amdgcn_mfma_f32_16x16x32_bf16((a), (b), (c), 0, 0, 0)
#define MFMA32(a, b, c) __builtin_amdgcn_mfma_f32_32x32x16_bf16((a), (b), (c), 0, 0, 0)
#define EXP2(x) __builtin_amdgcn_exp2f(x)

namespace {
constexpr int S_LEN = 2048;
constexpr int EMB   = 1024;
constexpr int HEADS = 16;
constexpr int HD    = 64;
constexpr float Q_PRESCALE = 1.44269504088896340736f / 32.0f;
constexpr float NEG_L2     = -4.5084e18f;   // -1e20 * log2(e)/32 -> exp2 = 0
}

__device__ __forceinline__ bf16x8 load8_cvt(const float* __restrict__ p) {
    const f32x4 a = *(const f32x4*)p;
    const f32x4 b = *(const f32x4*)(p + 4);
    bf16x8 r;
    r[0] = (bf16_t)a[0]; r[1] = (bf16_t)a[1]; r[2] = (bf16_t)a[2]; r[3] = (bf16_t)a[3];
    r[4] = (bf16_t)b[0]; r[5] = (bf16_t)b[1]; r[6] = (bf16_t)b[2]; r[7] = (bf16_t)b[3];
    return r;
}

__device__ __forceinline__ unsigned pk_bf16(float lo, float hi) {
    union { bf16_t h[2]; unsigned u; } u;
    u.h[0] = (bf16_t)lo; u.h[1] = (bf16_t)hi;
    return u.u;
}

// --------------------------------------------------------------------------
// Kernel 1: per-head projections (fp32 in -> bf16 out).
//   Qp row-major; Kf/Vf in MFMA-fragment-major order (lane-contiguous).
// --------------------------------------------------------------------------
__global__ __launch_bounds__(256) void proj_kernel(
    const float* __restrict__ values, const float* __restrict__ keys,
    const float* __restrict__ queries,
    const float* __restrict__ Wv, const float* __restrict__ Wk,
    const float* __restrict__ Wq,
    bf16_t* __restrict__ Qp, bf16_t* __restrict__ Kf, bf16_t* __restrict__ Vf)
{
    const int tid = threadIdx.x;
    const int w = tid >> 6, l = tid & 63, g = l >> 4, q15 = l & 15;
    const int b   = blockIdx.x;
    const int mat = b >> 10;
    const int rem = b & 1023;
    const int h   = rem >> 6;
    const int t0  = (((rem & 63) << 2) + w) << 4;
    const int n   = t0 >> 11;
    const int s0  = t0 & 2047;

    if (mat < 2) {
        const float* X = (mat == 0) ? queries : keys;
        const float* W = (mat == 0) ? Wq : Wk;
        const float scl = (mat == 0) ? Q_PRESCALE : 1.0f;
        const float* xr = X + (size_t)(t0 + q15) * EMB + h * HD + g * 8;
        bf16x8 a0 = load8_cvt(xr);
        bf16x8 a1 = load8_cvt(xr + 32);
        f32x4 acc[4];
        #pragma unroll
        for (int nt = 0; nt < 4; ++nt) acc[nt] = (f32x4){0.f, 0.f, 0.f, 0.f};
        #pragma unroll
        for (int nt = 0; nt < 4; ++nt) {
            const float* wr = W + (nt * 16 + q15) * HD + g * 8;
            bf16x8 b0 = load8_cvt(wr);
            bf16x8 b1 = load8_cvt(wr + 32);
            acc[nt] = MFMA16(a0, b0, acc[nt]);
            acc[nt] = MFMA16(a1, b1, acc[nt]);
        }
        if (mat == 0) {
            bf16_t* O = Qp + (size_t)(n * HEADS + h) * S_LEN * HD;
            #pragma unroll
            for (int nt = 0; nt < 4; ++nt)
                #pragma unroll
                for (int r = 0; r < 4; ++r)
                    O[(size_t)(s0 + g * 4 + r) * HD + nt * 16 + q15] = (bf16_t)(acc[nt][r] * scl);
        } else {
            bf16_t* O = Kf + (size_t)(n * HEADS + h) * S_LEN * HD;
            const int ktb  = s0 >> 5;
            const int lrow = s0 & 31;
            const int hi8  = (q15 >> 3) * 256 + (q15 & 7);
            #pragma unroll
            for (int nt = 0; nt < 4; ++nt)
                #pragma unroll
                for (int r = 0; r < 4; ++r)
                    O[(size_t)(ktb * 4 + nt) * 512 + hi8 + (lrow + g * 4 + r) * 8]
                        = (bf16_t)acc[nt][r];
        }
    } else {
        const float* xr = values + (size_t)(t0 + q15) * EMB + h * HD + g * 8;
        bf16x8 b0 = load8_cvt(xr);
        bf16x8 b1 = load8_cvt(xr + 32);
        bf16_t* O = Vf + (size_t)(n * HEADS + h) * S_LEN * HD;
        f32x4 acc[4];
        #pragma unroll
        for (int et = 0; et < 4; ++et) acc[et] = (f32x4){0.f, 0.f, 0.f, 0.f};
        #pragma unroll
        for (int et = 0; et < 4; ++et) {
            const float* wr = Wv + (et * 16 + q15) * HD + g * 8;
            bf16x8 a0 = load8_cvt(wr);
            bf16x8 a1 = load8_cvt(wr + 32);
            acc[et] = MFMA16(a0, b0, acc[et]);
            acc[et] = MFMA16(a1, b1, acc[et]);
        }
        const int kt2 = (s0 >> 6) * 2;
        const int ksl = (s0 >> 4) & 3;
        const int hi8 = (q15 >> 3) * 256 + (q15 & 7);
        #pragma unroll
        for (int et = 0; et < 4; ++et)
            #pragma unroll
            for (int r = 0; r < 4; ++r)
                O[(size_t)((kt2 + (et >> 1)) * 4 + ksl) * 512 + hi8
                  + ((et & 1) * 16 + g * 4 + r) * 8] = (bf16_t)acc[et][r];
    }
}

// --------------------------------------------------------------------------
// Kernel 2: flash attention — r19 configuration (validated 66.4us):
// fragment-major K/V, just-in-time loads (LDS staging r20 and register
// dbuf r16 both measured as regressions), raw v_exp_f32, shfl_xor P
// redistribution, max-free softmax, T5 s_setprio around MFMA clusters,
// (256,3), grid 512.
// --------------------------------------------------------------------------
__global__ __launch_bounds__(256, 3) void attn_kernel(
    const bf16_t* __restrict__ Qp, const bf16_t* __restrict__ Kf,
    const bf16_t* __restrict__ Vf, const int* __restrict__ mask,
    bf16_t* __restrict__ AO)
{
    __shared__ bf16_t plds[4][32][72];   // epilogue transpose only
    const int tid = threadIdx.x;
    const int w = tid >> 6, l = tid & 63;
    const int l31 = l & 31, hi = l >> 5;
    const int bid = blockIdx.x;
    const int nh = bid & 31, qt = bid >> 5;
    const int n = nh >> 4, h = nh & 15;
    const size_t hb = (size_t)nh * S_LEN * HD;
    const int qb = qt * 128 + w * 32;

    bf16x8 qf[4];
    {
        const bf16_t* qr = Qp + hb + (size_t)(qb + l31) * HD + hi * 8;
        #pragma unroll
        for (int d = 0; d < 4; ++d) qf[d] = *(const bf16x8*)(qr + d * 16);
    }

    const int* __restrict__ mrow = mask + n * S_LEN;
    const bf16_t* kp0 = Kf + hb + (size_t)l * 8;   // fragment-major, lane-contiguous
    const bf16_t* vp0 = Vf + hb + (size_t)l * 8;

    bool anyZero = false;
    {
        const int* mp = mrow + (l >> 1) * 64 + (l & 1) * 32;
        #pragma unroll
        for (int j = 0; j < 8; ++j) {
            const int4 mv = *(const int4*)(mp + 4 * j);
            anyZero |= (mv.x == 0) | (mv.y == 0) | (mv.z == 0) | (mv.w == 0);
        }
    }
    const unsigned long long maskbal = __ballot(anyZero);

    f32x16 acc0, acc1;
    #pragma unroll
    for (int i = 0; i < 16; ++i) { acc0[i] = 0.f; acc1[i] = 0.f; }
    float l_run = 0.0f;

    for (int kt = 0; kt < 32; ++kt) {
        // K A-fragments + V B-fragments, just-in-time, lane-contiguous
        bf16x8 kf[8], vf[8];
        {
            const bf16_t* pk = kp0 + (size_t)(kt * 8) * 512;
            const bf16_t* pv = vp0 + (size_t)(kt * 8) * 512;
            #pragma unroll
            for (int j = 0; j < 8; ++j) kf[j] = *(const bf16x8*)(pk + j * 512);
            #pragma unroll
            for (int j = 0; j < 8; ++j) vf[j] = *(const bf16x8*)(pv + j * 512);
        }

        // S^T = K · Q^T : two 32x32 blocks over 4 d-steps each
        f32x16 s0, s1;
        #pragma unroll
        for (int i = 0; i < 16; ++i) { s0[i] = 0.f; s1[i] = 0.f; }
        __builtin_amdgcn_s_setprio(1);
        #pragma unroll
        for (int d = 0; d < 4; ++d) s0 = MFMA32(kf[d],     qf[d], s0);
        #pragma unroll
        for (int d = 0; d < 4; ++d) s1 = MFMA32(kf[4 + d], qf[d], s1);
        __builtin_amdgcn_s_setprio(0);

        // masking: wave-uniform scalar test, rare path only
        if ((maskbal >> (2 * kt)) & 3ull) {
            const unsigned long long mb = __ballot(mrow[kt * 64 + l] != 0);
            #pragma unroll
            for (int r = 0; r < 16; ++r) {
                const int cr = (r & 3) + 8 * (r >> 2) + 4 * hi;
                if (!((mb >> cr) & 1ull))        s0[r] = NEG_L2;
                if (!((mb >> (32 + cr)) & 1ull)) s1[r] = NEG_L2;
            }
        }

        // p = exp2(s) via raw v_exp_f32; l accumulates per half-lane
        float ts0 = 0.f, ts1 = 0.f;
        #pragma unroll
        for (int r = 0; r < 16; ++r) {
            const float p0 = EXP2(s0[r]);
            const float p1 = EXP2(s1[r]);
            s0[r] = p0; s1[r] = p1;
            ts0 += p0; ts1 += p1;
        }
        l_run += ts0 + ts1;

        // P -> PV A-fragments: 2 shfl + selects per (b,t), in-register
        union U8 { unsigned u[4]; bf16x8 v; };
        bf16x8 pa[4];
        #pragma unroll
        for (int b = 0; b < 2; ++b) {
            #pragma unroll
            for (int t = 0; t < 2; ++t) {
                const int rb = t * 8;
                float e0, e1, e2, e3, e4, e5, e6, e7;
                if (b == 0) {
                    e0 = s0[rb]; e1 = s0[rb + 1]; e2 = s0[rb + 2]; e3 = s0[rb + 3];
                    e4 = s0[rb + 4]; e5 = s0[rb + 5]; e6 = s0[rb + 6]; e7 = s0[rb + 7];
                } else {
                    e0 = s1[rb]; e1 = s1[rb + 1]; e2 = s1[rb + 2]; e3 = s1[rb + 3];
                    e4 = s1[rb + 4]; e5 = s1[rb + 5]; e6 = s1[rb + 6]; e7 = s1[rb + 7];
                }
                const unsigned a01 = pk_bf16(e0, e1);
                const unsigned a23 = pk_bf16(e2, e3);
                const unsigned b01 = pk_bf16(e4, e5);
                const unsigned b23 = pk_bf16(e6, e7);
                const unsigned y1 = hi ? a01 : b01;
                const unsigned y2 = hi ? a23 : b23;
                const unsigned r1 = (unsigned)__shfl_xor((int)y1, 32);
                const unsigned r2 = (unsigned)__shfl_xor((int)y2, 32);
                U8 f;
                f.u[0] = hi ? r1 : a01;
                f.u[1] = hi ? r2 : a23;
                f.u[2] = hi ? b01 : r1;
                f.u[3] = hi ? b23 : r2;
                pa[2 * b + t] = f.v;
            }
        }

        __builtin_amdgcn_s_setprio(1);
        #pragma unroll
        for (int ksl = 0; ksl < 4; ++ksl) {
            acc0 = MFMA32(pa[ksl], vf[ksl],     acc0);
            acc1 = MFMA32(pa[ksl], vf[4 + ksl], acc1);
        }
        __builtin_amdgcn_s_setprio(0);
    }

    // epilogue: normalize, per-wave LDS transpose behind __syncthreads,
    // coalesced AO write
    const float l_tot = l_run + __shfl_xor(l_run, 32);   // per q = l31
    const float inv = 1.0f / l_tot;
    #pragma unroll
    for (int r = 0; r < 16; ++r) {
        const int cr = (r & 3) + 8 * (r >> 2) + 4 * hi;
        const float iq = __shfl(inv, cr);
        plds[w][cr][l31]      = (bf16_t)(acc0[r] * iq);
        plds[w][cr][32 + l31] = (bf16_t)(acc1[r] * iq);
    }
    __syncthreads();
    const int rr = l >> 1, c0 = (l & 1) * 32;
    const bf16x8 o0 = *(const bf16x8*)&plds[w][rr][c0];
    const bf16x8 o1 = *(const bf16x8*)&plds[w][rr][c0 + 8];
    const bf16x8 o2 = *(const bf16x8*)&plds[w][rr][c0 + 16];
    const bf16x8 o3 = *(const bf16x8*)&plds[w][rr][c0 + 24];
    bf16_t* op = AO + (size_t)(n * S_LEN + qb + rr) * EMB + h * HD + c0;
    *(bf16x8*)(op)      = o0;
    *(bf16x8*)(op + 8)  = o1;
    *(bf16x8*)(op + 16) = o2;
    *(bf16x8*)(op + 24) = o3;
}

// --------------------------------------------------------------------------
// Kernel 3: out = AO @ Wo^T + bo.  M=4096, N=1024, K=1024. fp32 out.
// 128x64 tile (512 blocks), BK=64, 4 waves (2x2, each 64x32).
// --------------------------------------------------------------------------
__global__ __launch_bounds__(256) void outproj_kernel(
    const bf16_t* __restrict__ X, const float* __restrict__ Wo,
    const float* __restrict__ bo, float* __restrict__ out)
{
    __shared__ bf16_t Xs[128 * 64];
    __shared__ bf16_t Ws[64 * 64];
    const int tid = threadIdx.x;
    const int w = tid >> 6, l = tid & 63, g = l >> 4, q15 = l & 15;
    const int m0 = (blockIdx.x >> 4) * 128;
    const int n0 = (blockIdx.x & 15) * 64;
    const int wm = (w >> 1) * 64, wn = (w & 1) * 32;

    f32x4 acc[4][2];
    #pragma unroll
    for (int i = 0; i < 4; ++i)
        #pragma unroll
        for (int j = 0; j < 2; ++j) acc[i][j] = (f32x4){0.f, 0.f, 0.f, 0.f};

    for (int k0 = 0; k0 < EMB; k0 += 64) {
        __syncthreads();
        #pragma unroll
        for (int j = 0; j < 4; ++j) {
            const int cid = tid + 256 * j;
            const int r = cid >> 3, pc = cid & 7;
            const int sw = (pc ^ (r & 7)) * 8;
            *(bf16x8*)&Xs[r * 64 + sw] =
                *(const bf16x8*)(X + (size_t)(m0 + r) * EMB + k0 + pc * 8);
        }
        #pragma unroll
        for (int j = 0; j < 2; ++j) {
            const int cid = tid + 256 * j;
            const int r = cid >> 3, pc = cid & 7;
            const int sw = (pc ^ (r & 7)) * 8;
            *(bf16x8*)&Ws[r * 64 + sw] =
                load8_cvt(Wo + (size_t)(n0 + r) * EMB + k0 + pc * 8);
        }
        __syncthreads();
        #pragma unroll
        for (int c = 0; c < 2; ++c) {
            bf16x8 av[4], bv[2];
            #pragma unroll
            for (int mt = 0; mt < 4; ++mt) {
                const int r = wm + mt * 16 + q15;
                av[mt] = *(const bf16x8*)&Xs[r * 64 + (((4 * c + g) ^ (r & 7)) * 8)];
            }
            #pragma unroll
            for (int nt = 0; nt < 2; ++nt) {
                const int r = wn + nt * 16 + q15;
                bv[nt] = *(const bf16x8*)&Ws[r * 64 + (((4 * c + g) ^ (r & 7)) * 8)];
            }
            #pragma unroll
            for (int mt = 0; mt < 4; ++mt)
                #pragma unroll
                for (int nt = 0; nt < 2; ++nt)
                    acc[mt][nt] = MFMA16(av[mt], bv[nt], acc[mt][nt]);
        }
    }

    float bias[2];
    #pragma unroll
    for (int nt = 0; nt < 2; ++nt) bias[nt] = bo[n0 + wn + nt * 16 + q15];
    #pragma unroll
    for (int mt = 0; mt < 4; ++mt)
        #pragma unroll
        for (int nt = 0; nt < 2; ++nt)
            #pragma unroll
            for (int r = 0; r < 4; ++r)
                out[(size_t)(m0 + wm + mt * 16 + g * 4 + r) * EMB + n0 + wn + nt * 16 + q15]
                    = acc[mt][nt][r] + bias[nt];
}

// --------------------------------------------------------------------------
extern "C" void kernel_launch(void* const* d_in, const int* in_sizes, int n_in,
                              void* d_out, int out_size, void* d_ws, size_t ws_size,
                              hipStream_t stream) {
    const float* values  = (const float*)d_in[0];
    const float* keys    = (const float*)d_in[1];
    const float* queries = (const float*)d_in[2];
    const int*   mask    = (const int*)d_in[3];
    const float* Wv      = (const float*)d_in[4];
    const float* Wk      = (const float*)d_in[5];
    const float* Wq      = (const float*)d_in[6];
    const float* Wo      = (const float*)d_in[7];
    const float* bo      = (const float*)d_in[8];
    float* out = (float*)d_out;

    // ws layout (bf16 elems): Qp[0,4M) Kf[4M,8M) Vf[8M,12M) AO[12M,16M)
    bf16_t* Qp = (bf16_t*)d_ws;
    bf16_t* Kf = Qp + (size_t)4194304;
    bf16_t* Vf = Kf + (size_t)4194304;
    bf16_t* AO = Vf + (size_t)4194304;

    proj_kernel<<<3072, 256, 0, stream>>>(values, keys, queries, Wv, Wk, Wq, Qp, Kf, Vf);
    attn_kernel<<<512, 256, 0, stream>>>(Qp, Kf, Vf, mask, AO);
    outproj_kernel<<<512, 256, 0, stream>>>(AO, Wo, bo, out);
}